// Round 7
// baseline (1895.064 us; speedup 1.0000x reference)
//
#include <hip/hip_runtime.h>
#include <cstdint>

// CapsuleLayer dynamic routing, MI355X. B=16,N=64,I=2048,D=32,E=16,R=3.
// b-logits = (sum_j v_j).u_hat -> never materialize b or u_hat in HBM;
// 3 streaming passes over W (256MB each).
// Block = 512 threads (8 waves), wave owns 8 n's, block owns 8 b's (b-half).
// amdgpu_waves_per_eu(4,4): 128-VGPR budget, kernel uses ~108 -> 4 waves/SIMD
// (round 6's (2,2) capped occupancy at 19.7% and left the chip latency-bound).
// Full i->i+1 W register double-buffer; i-loop unrolled x2 so the compiler
// renames buffers instead of copy+vmcnt(0) draining per iteration.
// Grid 512 = 256 i-chunks x 2 b-halves; halves paired 8 blockIdx apart so
// both land on the same XCD (round-robin) and share W through that L2.
// MODE1 stashes u_hat in 64KB LDS across the in-block softmax (per-thread
// float2 slots, conflict-free); DPP quad_perm reduce-scatter as validated.

#define B_ 16
#define N_ 64
#define I_ 2048
#define D_ 32
#define E_ 16
#define EPS_ 1e-7f
#define IPER_ 8
#define NCHUNK_ 256         // i-chunks
#define GRIDP_ 512          // pass grid = NCHUNK_ * 2 b-halves
#define SROW_ 2048          // b-stride in s/vtot = N_*D_
#define NOUT_ 32768         // B_*N_*D_
#define PSTRIDE_ 32768      // floats per i-chunk partial
#define WN4_ 262144         // float4 stride between n planes = I_*128

template <int CTRL>
__device__ __forceinline__ float dppf(float v) {
  return __int_as_float(
      __builtin_amdgcn_update_dpp(0, __float_as_int(v), CTRL, 0xF, 0xF, true));
}
// DPP ctrl: quad_perm[1,0,3,2]=0xB1 (xor1), quad_perm[2,3,0,1]=0x4E (xor2),
// row_ror:4=0x124, row_ror:8=0x128 (rows = 16 lanes).

// u_hat for b-quad k (k in {0,1}): lane ends owning b_loc=4k+q,
// d=dd (u0) and d=dd+16 (u1).
__device__ __forceinline__ void chunk_u(const float4 wa0, const float4 wa1,
                                        const float* __restrict__ xr,
                                        int k, int q, float& u0, float& u1)
{
  float p0[4], p1[4];
#pragma unroll
  for (int j = 0; j < 4; ++j) {
    const float4 xv = *(const float4*)&xr[(4 * k + j) * E_ + 4 * q];
    p0[j] = wa0.x * xv.x + wa0.y * xv.y + wa0.z * xv.z + wa0.w * xv.w;
    p1[j] = wa1.x * xv.x + wa1.y * xv.y + wa1.z * xv.z + wa1.w * xv.w;
  }
  {
    const float r0 = p0[0] + dppf<0xB1>(p0[0]);
    const float r1 = p0[1] + dppf<0xB1>(p0[1]);
    const float r2 = p0[2] + dppf<0xB1>(p0[2]);
    const float r3 = p0[3] + dppf<0xB1>(p0[3]);
    const float sa = (q & 1) ? r1 : r0;
    const float sb = (q & 1) ? r3 : r2;
    const float a0 = sa + dppf<0x4E>(sa);
    const float a1 = sb + dppf<0x4E>(sb);
    u0 = (q & 2) ? a1 : a0;
  }
  {
    const float r0 = p1[0] + dppf<0xB1>(p1[0]);
    const float r1 = p1[1] + dppf<0xB1>(p1[1]);
    const float r2 = p1[2] + dppf<0xB1>(p1[2]);
    const float r3 = p1[3] + dppf<0xB1>(p1[3]);
    const float sa = (q & 1) ? r1 : r0;
    const float sb = (q & 1) ? r3 : r2;
    const float a0 = sa + dppf<0x4E>(sa);
    const float a1 = sb + dppf<0x4E>(sb);
    u1 = (q & 2) ? a1 : a0;
  }
}

// MODE 0: c = 1/64 (softmax of zero logits); barrier-free i-loop.
// MODE 1: logits = vtot . u_hat (vtot in regs), softmax over n in block,
//         u_hat via per-thread LDS stash, phase B LDS-only.
template <int MODE>
__global__ __launch_bounds__(512)
__attribute__((amdgpu_waves_per_eu(4, 4)))
void caps_pass(
    const float* __restrict__ W,     // [N][I][D][E]
    const float* __restrict__ x,     // [B][I][E]
    const float* __restrict__ vtot,  // [B][N][D]
    float* __restrict__ out,         // partials base or s (atomic)
    int use_part)
{
  const int t = threadIdx.x;   // 0..511
  const int w = t >> 6;        // wave 0..7 -> n = 8w+nn
  const int l = t & 63;
  const int q = l & 3;         // e-quarter
  const int dd = l >> 2;       // d (0..15); also owns d+16

  // pair the two b-halves of an i-chunk 8 blockIdx apart (same XCD)
  const int orig = blockIdx.x;
  const int h = (orig >> 3) & 1;                    // b-half
  const int ic = (orig & 7) | ((orig >> 4) << 3);   // i-chunk 0..255
  const int i0 = ic * IPER_;

  __shared__ float x_lds[IPER_ * 8 * E_];  // 4 KB: [ii][b_loc][e]
  __shared__ float2 u_st[16 * 512];        // 64 KB: [(nn*2+k)*512 + t] (MODE1)
  __shared__ float l2[N_ * 33];            // logit row-partials [n][b_loc*4+r]
  __shared__ float c_lds[N_ * 9];          // c [n][b_loc], pad

  // preload x for all 8 i's, this block's 8 b's (the only MODE0 barrier)
  for (int j = t; j < IPER_ * 8 * E_; j += 512) {
    const int ii = j >> 7, bl = (j >> 4) & 7, e = j & 15;
    x_lds[j] = x[((size_t)(h * 8 + bl) * I_ + (i0 + ii)) * E_ + e];
  }
  __syncthreads();

  float acc0[8][2], acc1[8][2];   // [nn][k], b_loc=4k+q, d=dd / dd+16
#pragma unroll
  for (int nn = 0; nn < 8; ++nn)
#pragma unroll
    for (int k = 0; k < 2; ++k) { acc0[nn][k] = 0.f; acc1[nn][k] = 0.f; }

  float vt0[8][2], vt1[8][2];
  if (MODE == 1) {
#pragma unroll
    for (int nn = 0; nn < 8; ++nn)
#pragma unroll
      for (int k = 0; k < 2; ++k) {
        const size_t va = (size_t)(h * 8 + 4 * k + q) * SROW_ +
                          (size_t)(8 * w + nn) * D_ + dd;
        vt0[nn][k] = vtot[va];
        vt1[nn][k] = vtot[va + 16];
      }
  }

  const float4* Wbase = (const float4*)W + (((size_t)(8 * w) * I_ + i0) << 7);

  // current-i W tile (8 n x 2 float4) + next-i prefetch (renamed by unroll 2)
  float4 cw0[8], cw1[8], nw0[8], nw1[8];
#pragma unroll
  for (int nn = 0; nn < 8; ++nn) {
    const float4* Wf = Wbase + (size_t)nn * WN4_;
    cw0[nn] = Wf[l]; cw1[nn] = Wf[64 + l];
  }

#pragma unroll 2
  for (int ii = 0; ii < IPER_; ++ii) {
    if (ii + 1 < IPER_) {
#pragma unroll
      for (int nn = 0; nn < 8; ++nn) {
        const float4* Wf = Wbase + (size_t)nn * WN4_ + (ii + 1) * 128;
        nw0[nn] = Wf[l]; nw1[nn] = Wf[64 + l];
      }
    }
    const float* xr = &x_lds[ii * (8 * E_)];

    if (MODE == 0) {
#pragma unroll
      for (int nn = 0; nn < 8; ++nn)
#pragma unroll
        for (int k = 0; k < 2; ++k) {
          float u0, u1;
          chunk_u(cw0[nn], cw1[nn], xr, k, q, u0, u1);
          acc0[nn][k] += u0;
          acc1[nn][k] += u1;
        }
    } else {
      // ---- phase A: u_hat, stash, logits ----
#pragma unroll
      for (int nn = 0; nn < 8; ++nn) {
#pragma unroll
        for (int k = 0; k < 2; ++k) {
          float u0, u1;
          chunk_u(cw0[nn], cw1[nn], xr, k, q, u0, u1);
          u_st[(nn * 2 + k) * 512 + t] = make_float2(u0, u1);
          float lp = vt0[nn][k] * u0 + vt1[nn][k] * u1;
          lp += dppf<0x124>(lp);   // + ror4
          lp += dppf<0x128>(lp);   // + ror8 -> sum over row's 4 dd
          if ((l & 12) == 0)       // one writer per (row, b_loc)
            l2[(8 * w + nn) * 33 + (4 * k + q) * 4 + (l >> 4)] = lp;
        }
      }
      __syncthreads();
      {
        // wave bw handles b_loc=bw, lane j = n
        const int bw = t >> 6, j = t & 63;
        const int base = j * 33 + bw * 4;
        const float raw = l2[base] + l2[base + 1] + l2[base + 2] + l2[base + 3];
        float m = raw;
#pragma unroll
        for (int off = 32; off; off >>= 1) m = fmaxf(m, __shfl_xor(m, off));
        const float e = __expf(raw - m);
        float den = e;
#pragma unroll
        for (int off = 32; off; off >>= 1) den += __shfl_xor(den, off);
        c_lds[j * 9 + bw] = e / den;
      }
      __syncthreads();
      // ---- phase B: LDS-only — stash read, apply c, accumulate ----
#pragma unroll
      for (int nn = 0; nn < 8; ++nn)
#pragma unroll
        for (int k = 0; k < 2; ++k) {
          const float2 u = u_st[(nn * 2 + k) * 512 + t];
          const float cc = c_lds[(8 * w + nn) * 9 + 4 * k + q];
          acc0[nn][k] += cc * u.x;
          acc1[nn][k] += cc * u.y;
        }
    }
#pragma unroll
    for (int nn = 0; nn < 8; ++nn) { cw0[nn] = nw0[nn]; cw1[nn] = nw1[nn]; }
  }

  // store: partial slice for this i-chunk (b-halves disjoint) or atomic
  const float sc = (MODE == 0) ? (1.f / 64.f) : 1.f;
  float* base = out + (use_part ? (size_t)ic * PSTRIDE_ : 0);
#pragma unroll
  for (int nn = 0; nn < 8; ++nn) {
#pragma unroll
    for (int k = 0; k < 2; ++k) {
      const int b = h * 8 + 4 * k + q, n = 8 * w + nn;
      const size_t a = (size_t)b * SROW_ + (size_t)n * D_ + dd;
      if (use_part) {
        base[a] = acc0[nn][k] * sc;
        base[a + 16] = acc1[nn][k] * sc;
      } else {
        atomicAdd(&base[a], acc0[nn][k] * sc);
        atomicAdd(&base[a + 16], acc1[nn][k] * sc);
      }
    }
  }
}

// Fused partial-reduce + squash. g = (b*64+n)*32 + d; row = 32 lanes.
// ACCMODE 0: dst[g] = squash; 1: dst[g] += squash.
template <int ACCMODE>
__global__ __launch_bounds__(256) void reduce_squash(
    const float* __restrict__ part, const float* __restrict__ s_single,
    float* __restrict__ dst, int use_part)
{
  const int g = blockIdx.x * 256 + threadIdx.x;  // 0..32767
  float sum;
  if (use_part) {
    sum = 0.f;
#pragma unroll 8
    for (int p = 0; p < NCHUNK_; ++p) sum += part[(size_t)p * PSTRIDE_ + g];
  } else {
    sum = s_single[g];
  }
  float s2 = sum * sum;  // reduce over the row's 32 lanes (xor<32 stays in row)
#pragma unroll
  for (int off = 16; off; off >>= 1) s2 += __shfl_xor(s2, off);
  const float f = s2 / ((1.f + s2) * sqrtf(s2 + EPS_));
  if (ACCMODE == 0) dst[g] = sum * f;
  else dst[g] += sum * f;
}

extern "C" void kernel_launch(void* const* d_in, const int* in_sizes, int n_in,
                              void* d_out, int out_size, void* d_ws, size_t ws_size,
                              hipStream_t stream)
{
  const float* x = (const float*)d_in[0];  // [16][2048][16]
  const float* W = (const float*)d_in[1];  // [64][2048][32][16]
  float* s = (float*)d_out;                // [b][n][d] output
  float* vtot = (float*)d_ws;              // 32768 floats
  float* part = vtot + NOUT_;              // 256 * 32768 floats if available

  const size_t need =
      ((size_t)NOUT_ + (size_t)NCHUNK_ * PSTRIDE_) * sizeof(float);
  const int use_part = (ws_size >= need) ? 1 : 0;
  float* pass_out = use_part ? part : s;
  const size_t sbytes = (size_t)NOUT_ * sizeof(float);

  // Round 1: c = 1/64 -> vtot = v0
  if (!use_part) hipMemsetAsync(s, 0, sbytes, stream);
  caps_pass<0><<<GRIDP_, 512, 0, stream>>>(W, x, vtot, pass_out, use_part);
  reduce_squash<0><<<128, 256, 0, stream>>>(part, s, vtot, use_part);

  // Round 2: logits = v0 . u_hat -> vtot += v1
  if (!use_part) hipMemsetAsync(s, 0, sbytes, stream);
  caps_pass<1><<<GRIDP_, 512, 0, stream>>>(W, x, vtot, pass_out, use_part);
  reduce_squash<1><<<128, 256, 0, stream>>>(part, s, vtot, use_part);

  // Round 3: logits = (v0+v1) . u_hat -> final squash into d_out
  if (!use_part) hipMemsetAsync(s, 0, sbytes, stream);
  caps_pass<1><<<GRIDP_, 512, 0, stream>>>(W, x, vtot, pass_out, use_part);
  reduce_squash<0><<<128, 256, 0, stream>>>(part, s, s, use_part);
}

// Round 8
// 312.965 us; speedup vs baseline: 6.0552x; 6.0552x over previous
//
#include <hip/hip_runtime.h>
#include <cstdint>

// CapsuleLayer dynamic routing, MI355X. B=16,N=64,I=2048,D=32,E=16,R=3.
// b-logits = (sum_j v_j).u_hat -> never materialize b or u_hat in HBM;
// 3 streaming passes over W (256MB each).
// Block = 512 threads (8 waves), wave owns 8 n's, block owns 8 b's (b-half).
// waves_per_eu(4,4): budget 128 VGPR, 4 waves/SIMD, 2 blocks/CU (LDS 79KBx2).
// NO explicit W double-buffer (round 7: unroll-2 + dbuf -> allocator collapse
// to 64 VGPR + 1.1GB spill traffic). W loaded in 4 groups of 2 n per i;
// latency hidden by 16 resident waves/CU (TLP), not in-wave pipelining.
// Grid 512 = 256 i-chunks x 2 b-halves; halves paired 8 blockIdx apart so
// both land on the same XCD (round-robin) and share W through that L2.
// MODE1 stashes u_hat in 64KB LDS across the in-block softmax (per-thread
// float2 slots, 2-way-free); vtot in 32 regs (pure-W vmcnt stream);
// DPP quad_perm reduce-scatter as validated since round 2.

#define B_ 16
#define N_ 64
#define I_ 2048
#define D_ 32
#define E_ 16
#define EPS_ 1e-7f
#define IPER_ 8
#define NCHUNK_ 256         // i-chunks
#define GRIDP_ 512          // pass grid = NCHUNK_ * 2 b-halves
#define SROW_ 2048          // b-stride in s/vtot = N_*D_
#define NOUT_ 32768         // B_*N_*D_
#define PSTRIDE_ 32768      // floats per i-chunk partial
#define WN4_ 262144         // float4 stride between n planes = I_*128

template <int CTRL>
__device__ __forceinline__ float dppf(float v) {
  return __int_as_float(
      __builtin_amdgcn_update_dpp(0, __float_as_int(v), CTRL, 0xF, 0xF, true));
}
// DPP ctrl: quad_perm[1,0,3,2]=0xB1 (xor1), quad_perm[2,3,0,1]=0x4E (xor2),
// row_ror:4=0x124, row_ror:8=0x128 (rows = 16 lanes).

// u_hat for b-quad k (k in {0,1}): lane ends owning b_loc=4k+q,
// d=dd (u0) and d=dd+16 (u1).
__device__ __forceinline__ void chunk_u(const float4 wa0, const float4 wa1,
                                        const float* __restrict__ xr,
                                        int k, int q, float& u0, float& u1)
{
  float p0[4], p1[4];
#pragma unroll
  for (int j = 0; j < 4; ++j) {
    const float4 xv = *(const float4*)&xr[(4 * k + j) * E_ + 4 * q];
    p0[j] = wa0.x * xv.x + wa0.y * xv.y + wa0.z * xv.z + wa0.w * xv.w;
    p1[j] = wa1.x * xv.x + wa1.y * xv.y + wa1.z * xv.z + wa1.w * xv.w;
  }
  {
    const float r0 = p0[0] + dppf<0xB1>(p0[0]);
    const float r1 = p0[1] + dppf<0xB1>(p0[1]);
    const float r2 = p0[2] + dppf<0xB1>(p0[2]);
    const float r3 = p0[3] + dppf<0xB1>(p0[3]);
    const float sa = (q & 1) ? r1 : r0;
    const float sb = (q & 1) ? r3 : r2;
    const float a0 = sa + dppf<0x4E>(sa);
    const float a1 = sb + dppf<0x4E>(sb);
    u0 = (q & 2) ? a1 : a0;
  }
  {
    const float r0 = p1[0] + dppf<0xB1>(p1[0]);
    const float r1 = p1[1] + dppf<0xB1>(p1[1]);
    const float r2 = p1[2] + dppf<0xB1>(p1[2]);
    const float r3 = p1[3] + dppf<0xB1>(p1[3]);
    const float sa = (q & 1) ? r1 : r0;
    const float sb = (q & 1) ? r3 : r2;
    const float a0 = sa + dppf<0x4E>(sa);
    const float a1 = sb + dppf<0x4E>(sb);
    u1 = (q & 2) ? a1 : a0;
  }
}

// MODE 0: c = 1/64 (softmax of zero logits); barrier-free i-loop.
// MODE 1: logits = vtot . u_hat (vtot in regs), softmax over n in block,
//         u_hat via per-thread LDS stash, phase B LDS-only.
template <int MODE>
__global__ __launch_bounds__(512)
__attribute__((amdgpu_waves_per_eu(4, 4)))
void caps_pass(
    const float* __restrict__ W,     // [N][I][D][E]
    const float* __restrict__ x,     // [B][I][E]
    const float* __restrict__ vtot,  // [B][N][D]
    float* __restrict__ out,         // partials base or s (atomic)
    int use_part)
{
  const int t = threadIdx.x;   // 0..511
  const int w = t >> 6;        // wave 0..7 -> n = 8w+nn
  const int l = t & 63;
  const int q = l & 3;         // e-quarter
  const int dd = l >> 2;       // d (0..15); also owns d+16

  // pair the two b-halves of an i-chunk 8 blockIdx apart (same XCD)
  const int orig = blockIdx.x;
  const int h = (orig >> 3) & 1;                    // b-half
  const int ic = (orig & 7) | ((orig >> 4) << 3);   // i-chunk 0..255
  const int i0 = ic * IPER_;

  __shared__ float x_lds[IPER_ * 8 * E_];  // 4 KB: [ii][b_loc][e]
  __shared__ float2 u_st[16 * 512];        // 64 KB: [(nn*2+k)*512 + t] (MODE1)
  __shared__ float l2[N_ * 33];            // logit row-partials [n][b_loc*4+r]
  __shared__ float c_lds[N_ * 9];          // c [n][b_loc], pad

  // preload x for all 8 i's, this block's 8 b's (the only MODE0 barrier)
  for (int j = t; j < IPER_ * 8 * E_; j += 512) {
    const int ii = j >> 7, bl = (j >> 4) & 7, e = j & 15;
    x_lds[j] = x[((size_t)(h * 8 + bl) * I_ + (i0 + ii)) * E_ + e];
  }
  __syncthreads();

  float acc0[8][2], acc1[8][2];   // [nn][k], b_loc=4k+q, d=dd / dd+16
#pragma unroll
  for (int nn = 0; nn < 8; ++nn)
#pragma unroll
    for (int k = 0; k < 2; ++k) { acc0[nn][k] = 0.f; acc1[nn][k] = 0.f; }

  float vt0[8][2], vt1[8][2];
  if (MODE == 1) {
#pragma unroll
    for (int nn = 0; nn < 8; ++nn)
#pragma unroll
      for (int k = 0; k < 2; ++k) {
        const size_t va = (size_t)(h * 8 + 4 * k + q) * SROW_ +
                          (size_t)(8 * w + nn) * D_ + dd;
        vt0[nn][k] = vtot[va];
        vt1[nn][k] = vtot[va + 16];
      }
  }

  const float4* Wbase = (const float4*)W + (((size_t)(8 * w) * I_ + i0) << 7);

#pragma unroll 1
  for (int ii = 0; ii < IPER_; ++ii) {
    const float* xr = &x_lds[ii * (8 * E_)];

    // ---- phase A: W in 4 groups of 2 n (16 VGPR in flight per group) ----
#pragma unroll
    for (int g = 0; g < 4; ++g) {
      const float4* W0 = Wbase + (size_t)(2 * g) * WN4_ + ii * 128;
      const float4* W1 = W0 + WN4_;
      const float4 a0 = W0[l], a1 = W0[64 + l];
      const float4 b0 = W1[l], b1 = W1[64 + l];
#pragma unroll
      for (int s = 0; s < 2; ++s) {
        const int nn = 2 * g + s;
        const float4 wv0 = s ? b0 : a0;
        const float4 wv1 = s ? b1 : a1;
#pragma unroll
        for (int k = 0; k < 2; ++k) {
          float u0, u1;
          chunk_u(wv0, wv1, xr, k, q, u0, u1);
          if (MODE == 0) {
            acc0[nn][k] += u0;
            acc1[nn][k] += u1;
          } else {
            u_st[(nn * 2 + k) * 512 + t] = make_float2(u0, u1);
            float lp = vt0[nn][k] * u0 + vt1[nn][k] * u1;
            lp += dppf<0x124>(lp);   // + ror4
            lp += dppf<0x128>(lp);   // + ror8 -> sum over row's 4 dd
            if ((l & 12) == 0)       // one writer per (row, b_loc)
              l2[(8 * w + nn) * 33 + (4 * k + q) * 4 + (l >> 4)] = lp;
          }
        }
      }
    }

    if (MODE == 1) {
      __syncthreads();
      {
        // wave bw handles b_loc=bw, lane j = n
        const int bw = t >> 6, j = t & 63;
        const int base = j * 33 + bw * 4;
        const float raw = l2[base] + l2[base + 1] + l2[base + 2] + l2[base + 3];
        float m = raw;
#pragma unroll
        for (int off = 32; off; off >>= 1) m = fmaxf(m, __shfl_xor(m, off));
        const float e = __expf(raw - m);
        float den = e;
#pragma unroll
        for (int off = 32; off; off >>= 1) den += __shfl_xor(den, off);
        c_lds[j * 9 + bw] = e / den;
      }
      __syncthreads();
      // ---- phase B: LDS-only — stash read, apply c, accumulate ----
#pragma unroll
      for (int nn = 0; nn < 8; ++nn)
#pragma unroll
        for (int k = 0; k < 2; ++k) {
          const float2 u = u_st[(nn * 2 + k) * 512 + t];
          const float cc = c_lds[(8 * w + nn) * 9 + 4 * k + q];
          acc0[nn][k] += cc * u.x;
          acc1[nn][k] += cc * u.y;
        }
    }
  }

  // store: partial slice for this i-chunk (b-halves disjoint) or atomic
  const float sc = (MODE == 0) ? (1.f / 64.f) : 1.f;
  float* base = out + (use_part ? (size_t)ic * PSTRIDE_ : 0);
#pragma unroll
  for (int nn = 0; nn < 8; ++nn) {
#pragma unroll
    for (int k = 0; k < 2; ++k) {
      const int b = h * 8 + 4 * k + q, n = 8 * w + nn;
      const size_t a = (size_t)b * SROW_ + (size_t)n * D_ + dd;
      if (use_part) {
        base[a] = acc0[nn][k] * sc;
        base[a + 16] = acc1[nn][k] * sc;
      } else {
        atomicAdd(&base[a], acc0[nn][k] * sc);
        atomicAdd(&base[a + 16], acc1[nn][k] * sc);
      }
    }
  }
}

// Fused partial-reduce + squash. g = (b*64+n)*32 + d; row = 32 lanes.
// ACCMODE 0: dst[g] = squash; 1: dst[g] += squash.
template <int ACCMODE>
__global__ __launch_bounds__(256) void reduce_squash(
    const float* __restrict__ part, const float* __restrict__ s_single,
    float* __restrict__ dst, int use_part)
{
  const int g = blockIdx.x * 256 + threadIdx.x;  // 0..32767
  float sum;
  if (use_part) {
    sum = 0.f;
#pragma unroll 8
    for (int p = 0; p < NCHUNK_; ++p) sum += part[(size_t)p * PSTRIDE_ + g];
  } else {
    sum = s_single[g];
  }
  float s2 = sum * sum;  // reduce over the row's 32 lanes (xor<32 stays in row)
#pragma unroll
  for (int off = 16; off; off >>= 1) s2 += __shfl_xor(s2, off);
  const float f = s2 / ((1.f + s2) * sqrtf(s2 + EPS_));
  if (ACCMODE == 0) dst[g] = sum * f;
  else dst[g] += sum * f;
}

extern "C" void kernel_launch(void* const* d_in, const int* in_sizes, int n_in,
                              void* d_out, int out_size, void* d_ws, size_t ws_size,
                              hipStream_t stream)
{
  const float* x = (const float*)d_in[0];  // [16][2048][16]
  const float* W = (const float*)d_in[1];  // [64][2048][32][16]
  float* s = (float*)d_out;                // [b][n][d] output
  float* vtot = (float*)d_ws;              // 32768 floats
  float* part = vtot + NOUT_;              // 256 * 32768 floats if available

  const size_t need =
      ((size_t)NOUT_ + (size_t)NCHUNK_ * PSTRIDE_) * sizeof(float);
  const int use_part = (ws_size >= need) ? 1 : 0;
  float* pass_out = use_part ? part : s;
  const size_t sbytes = (size_t)NOUT_ * sizeof(float);

  // Round 1: c = 1/64 -> vtot = v0
  if (!use_part) hipMemsetAsync(s, 0, sbytes, stream);
  caps_pass<0><<<GRIDP_, 512, 0, stream>>>(W, x, vtot, pass_out, use_part);
  reduce_squash<0><<<128, 256, 0, stream>>>(part, s, vtot, use_part);

  // Round 2: logits = v0 . u_hat -> vtot += v1
  if (!use_part) hipMemsetAsync(s, 0, sbytes, stream);
  caps_pass<1><<<GRIDP_, 512, 0, stream>>>(W, x, vtot, pass_out, use_part);
  reduce_squash<1><<<128, 256, 0, stream>>>(part, s, vtot, use_part);

  // Round 3: logits = (v0+v1) . u_hat -> final squash into d_out
  if (!use_part) hipMemsetAsync(s, 0, sbytes, stream);
  caps_pass<1><<<GRIDP_, 512, 0, stream>>>(W, x, vtot, pass_out, use_part);
  reduce_squash<0><<<128, 256, 0, stream>>>(part, s, s, use_part);
}